// Round 4
// baseline (666.382 us; speedup 1.0000x reference)
//
#include <hip/hip_runtime.h>

#define H 512
#define W 512
#define NIMG 128
#define NBAND 16            // y-bands per image, 32 rows each
#define BR (H / NBAND)      // 32 output rows per block

#define YHR_OFF ((long)NIMG * H * W)                      // 33554432
#define BSTRIDE ((long)(H / 2) * (W / 2))                 // 65536
#define YH_SIZE ((long)NIMG * 6 * BSTRIDE)                // 50331648
#define YHI_OFF (YHR_OFF + YH_SIZE)                       // 83886080

__device__ __forceinline__ int reflect512(int g) {
    // symmetric (edge-inclusive) reflection; single fold valid for -512<g<1024
    g = (g < 0) ? (-1 - g) : g;
    g = (g > H - 1) ? (2 * H - 1 - g) : g;
    return g;
}

__device__ __forceinline__ float4 f4fma(float s, float4 a, float4 acc) {
    acc.x = fmaf(s, a.x, acc.x);
    acc.y = fmaf(s, a.y, acc.y);
    acc.z = fmaf(s, a.z, acc.z);
    acc.w = fmaf(s, a.w, acc.w);
    return acc;
}

// row filter FMA part: A = cols cg-4..cg-1, B = cg..cg+3, C = cg+4..cg+7
// lo[k] (5-tap, p=2) and hi[k] (7-tap, p=3) for out cols cg..cg+3
__device__ __forceinline__ void rowcomp(float4 A, float4 Bv, float4 C,
                                        const float* c0, const float* c1,
                                        float4& lo, float4& hi) {
    float f1 = A.y, f2 = A.z, f3 = A.w;
    float f4 = Bv.x, f5 = Bv.y, f6 = Bv.z, f7 = Bv.w;
    float f8 = C.x, f9 = C.y, f10 = C.z;
    lo.x = c0[0]*f2 + c0[1]*f3 + c0[2]*f4 + c0[3]*f5 + c0[4]*f6;
    lo.y = c0[0]*f3 + c0[1]*f4 + c0[2]*f5 + c0[3]*f6 + c0[4]*f7;
    lo.z = c0[0]*f4 + c0[1]*f5 + c0[2]*f6 + c0[3]*f7 + c0[4]*f8;
    lo.w = c0[0]*f5 + c0[1]*f6 + c0[2]*f7 + c0[3]*f8 + c0[4]*f9;
    hi.x = c1[0]*f1 + c1[1]*f2 + c1[2]*f3 + c1[3]*f4 + c1[4]*f5 + c1[5]*f6 + c1[6]*f7;
    hi.y = c1[0]*f2 + c1[1]*f3 + c1[2]*f4 + c1[3]*f5 + c1[4]*f6 + c1[5]*f7 + c1[6]*f8;
    hi.z = c1[0]*f3 + c1[1]*f4 + c1[2]*f5 + c1[3]*f6 + c1[4]*f7 + c1[5]*f8 + c1[6]*f9;
    hi.w = c1[0]*f4 + c1[1]*f5 + c1[2]*f6 + c1[3]*f7 + c1[4]*f8 + c1[5]*f9 + c1[6]*f10;
}

__global__ __launch_bounds__(128, 3)
void dtcwt_fwd1(const float* __restrict__ x,
                const float* __restrict__ h0o,
                const float* __restrict__ h1o,
                float* __restrict__ out)
{
    const int t   = threadIdx.x;       // 0..127, owns cols cg..cg+3 (full width)
    const int cg  = t * 4;
    const int ys  = blockIdx.x * BR;   // first output row of this band
    const int img = blockIdx.y;
    const bool e0 = (t == 0), e1 = (t == 127);

    float c0[5], c1[7];
#pragma unroll
    for (int j = 0; j < 5; ++j) c0[j] = h0o[j];
#pragma unroll
    for (int j = 0; j < 7; ++j) c1[j] = h1o[j];

    const long ibase = (long)img * (H * W);
    const float* __restrict__ xi = x + ibase;
    float* __restrict__ yl  = out + ibase;
    float* __restrict__ yhr = out + YHR_OFF + (long)img * 6 * BSTRIDE;
    float* __restrict__ yhi = out + YHI_OFF + (long)img * 6 * BSTRIDE;
    const float sc = 0.70710678118654752440f;

    // 8-deep register ring of row-filter results (rows yr0-3 .. yr0+4).
    // ALL indices compile-time after unroll -> stays in VGPRs.
    float4 wlo[8], whi[8];

    // ---- init: rows ys-3 .. ys+4 into slots 0..7 ----
#pragma unroll
    for (int p = 0; p < 8; ++p) {
        const float* rp = xi + (long)reflect512(ys - 3 + p) * W + cg;
        float4 Bv = *(const float4*)rp;
        float4 Ar = *(const float4*)(e0 ? rp : rp - 4);   // clamped addr, always valid
        float4 Cr = *(const float4*)(e1 ? rp : rp + 4);
        float4 rB = make_float4(Bv.w, Bv.z, Bv.y, Bv.x);  // x-reflection = reversed B
        float4 Av = e0 ? rB : Ar;
        float4 Cv = e1 ? rB : Cr;
        rowcomp(Av, Bv, Cv, c0, c1, wlo[p], whi[p]);
    }

    for (int qo = 0; qo < 4; ++qo) {
#pragma unroll
        for (int qi = 0; qi < 4; ++qi) {
            const int q   = qo * 4 + qi;
            const int yr0 = ys + 2 * q;          // even output row of this step
            const int b0  = (2 * qi) & 7;        // ring base (compile-time)
            const int b1  = (b0 + 1) & 7;

            // ---- 1) early-issue loads for the two NEW rows (yr0+5, yr0+6);
            //        latency hides under the ~240 col-filter FMAs below ----
            const float* rp0 = xi + (long)reflect512(yr0 + 5) * W + cg;
            const float* rp1 = xi + (long)reflect512(yr0 + 6) * W + cg;
            float4 B0 = *(const float4*)rp0;
            float4 A0r = *(const float4*)(e0 ? rp0 : rp0 - 4);
            float4 C0r = *(const float4*)(e1 ? rp0 : rp0 + 4);
            float4 B1 = *(const float4*)rp1;
            float4 A1r = *(const float4*)(e0 ? rp1 : rp1 - 4);
            float4 C1r = *(const float4*)(e1 ? rp1 : rp1 + 4);

            // ---- 2) column filters on current window ----
            // LoLo row yr0 uses lo rows yr0-2..yr0+2 -> ring pos 1..5; row yr1 -> pos 2..6
            float4 ll0 = make_float4(0.f, 0.f, 0.f, 0.f), ll1 = ll0;
#pragma unroll
            for (int j = 0; j < 5; ++j) {
                ll0 = f4fma(c0[j], wlo[(b0 + 1 + j) & 7], ll0);
                ll1 = f4fma(c0[j], wlo[(b0 + 2 + j) & 7], ll1);
            }
            {   // Yl: 2 KB contiguous per row per block
                const long ylb = (long)yr0 * W + cg;
                *(float4*)&yl[ylb]     = ll0;
                *(float4*)&yl[ylb + W] = ll1;
            }

            const long hb = (long)(yr0 >> 1) * (W / 2) + 2 * t;

            // LoHi rows: 7-tap over lo rows yr0-3..yr0+3 -> pos 0..6; yr1 -> pos 1..7
            {
                float4 lh0 = make_float4(0.f, 0.f, 0.f, 0.f), lh1 = lh0;
#pragma unroll
                for (int j = 0; j < 7; ++j) {
                    lh0 = f4fma(c1[j], wlo[(b0 + j) & 7],     lh0);
                    lh1 = f4fma(c1[j], wlo[(b0 + 1 + j) & 7], lh1);
                }
                // bands 0 (z1) and 5 (z2) from LoHi
                *(float2*)&yhr[hb + 0 * BSTRIDE] = make_float2((lh0.x - lh1.y) * sc, (lh0.z - lh1.w) * sc);
                *(float2*)&yhi[hb + 0 * BSTRIDE] = make_float2((lh0.y + lh1.x) * sc, (lh0.w + lh1.z) * sc);
                *(float2*)&yhr[hb + 5 * BSTRIDE] = make_float2((lh0.x + lh1.y) * sc, (lh0.z + lh1.w) * sc);
                *(float2*)&yhi[hb + 5 * BSTRIDE] = make_float2((lh0.y - lh1.x) * sc, (lh0.w - lh1.z) * sc);
            }
            // HiLo rows: 5-tap over hi rows -> pos 1..5 / 2..6
            {
                float4 hl0 = make_float4(0.f, 0.f, 0.f, 0.f), hl1 = hl0;
#pragma unroll
                for (int j = 0; j < 5; ++j) {
                    hl0 = f4fma(c0[j], whi[(b0 + 1 + j) & 7], hl0);
                    hl1 = f4fma(c0[j], whi[(b0 + 2 + j) & 7], hl1);
                }
                // bands 2 (z1) and 3 (z2) from HiLo
                *(float2*)&yhr[hb + 2 * BSTRIDE] = make_float2((hl0.x - hl1.y) * sc, (hl0.z - hl1.w) * sc);
                *(float2*)&yhi[hb + 2 * BSTRIDE] = make_float2((hl0.y + hl1.x) * sc, (hl0.w + hl1.z) * sc);
                *(float2*)&yhr[hb + 3 * BSTRIDE] = make_float2((hl0.x + hl1.y) * sc, (hl0.z + hl1.w) * sc);
                *(float2*)&yhi[hb + 3 * BSTRIDE] = make_float2((hl0.y - hl1.x) * sc, (hl0.w - hl1.z) * sc);
            }
            // HiHi rows: 7-tap over hi rows -> pos 0..6 / 1..7
            {
                float4 hh0 = make_float4(0.f, 0.f, 0.f, 0.f), hh1 = hh0;
#pragma unroll
                for (int j = 0; j < 7; ++j) {
                    hh0 = f4fma(c1[j], whi[(b0 + j) & 7],     hh0);
                    hh1 = f4fma(c1[j], whi[(b0 + 1 + j) & 7], hh1);
                }
                // bands 1 (z1) and 4 (z2) from HiHi
                *(float2*)&yhr[hb + 1 * BSTRIDE] = make_float2((hh0.x - hh1.y) * sc, (hh0.z - hh1.w) * sc);
                *(float2*)&yhi[hb + 1 * BSTRIDE] = make_float2((hh0.y + hh1.x) * sc, (hh0.w + hh1.z) * sc);
                *(float2*)&yhr[hb + 4 * BSTRIDE] = make_float2((hh0.x + hh1.y) * sc, (hh0.z + hh1.w) * sc);
                *(float2*)&yhi[hb + 4 * BSTRIDE] = make_float2((hh0.y - hh1.x) * sc, (hh0.w - hh1.z) * sc);
            }

            // ---- 3) row filter the staged rows; overwrite oldest ring slots ----
            {
                float4 rB0 = make_float4(B0.w, B0.z, B0.y, B0.x);
                float4 A0 = e0 ? rB0 : A0r;
                float4 C0 = e1 ? rB0 : C0r;
                rowcomp(A0, B0, C0, c0, c1, wlo[b0], whi[b0]);
                float4 rB1 = make_float4(B1.w, B1.z, B1.y, B1.x);
                float4 A1 = e0 ? rB1 : A1r;
                float4 C1 = e1 ? rB1 : C1r;
                rowcomp(A1, B1, C1, c0, c1, wlo[b1], whi[b1]);
            }
        }
    }
}

extern "C" void kernel_launch(void* const* d_in, const int* in_sizes, int n_in,
                              void* d_out, int out_size, void* d_ws, size_t ws_size,
                              hipStream_t stream) {
    const float* x   = (const float*)d_in[0];
    const float* h0o = (const float*)d_in[1];
    const float* h1o = (const float*)d_in[2];
    float* out = (float*)d_out;
    dim3 grid(NBAND, NIMG);            // 16 x 128 = 2048 blocks, 128 thr each
    dtcwt_fwd1<<<grid, dim3(128), 0, stream>>>(x, h0o, h1o, out);
}